// Round 6
// baseline (2710.270 us; speedup 1.0000x reference)
//
#include <hip/hip_runtime.h>
#include <stdint.h>
#include <stddef.h>

#define NB 1024
#define TB 1024
#define D_IN 6
#define UNITS 64
#define WIDTH 128
#define DOUT 6
#define EPSF 1e-8f
#define SPB 16          // samples per block (one 16-row MFMA tile) -- 64 blocks
#define LDK0 108        // c0 row stride (halfs): conflict-free (54 dw == 22 mod 32)
#define LDK 140         // cP/cQ/cG row stride (halfs): conflict-free (70 dw == 6 mod 32)

typedef _Float16 v8h __attribute__((ext_vector_type(8)));
typedef float v4f __attribute__((ext_vector_type(4)));

#define MFMAH(A,Bf,C) __builtin_amdgcn_mfma_f32_16x16x32_f16((A),(Bf),(C),0,0,0)

// LDS-only barrier: orders LDS across the block, does NOT drain vmcnt.
#define BARRIER_LDS() asm volatile("s_waitcnt lgkmcnt(0)\n\ts_barrier" ::: "memory")

#define C2L2E  2.8853900817779268f    // 2*log2(e)
#define L2E    1.4426950408889634f    // log2(e)
#define NEGL2E (-1.4426950408889634f)

__device__ __forceinline__ float rcp_fast(float x){ return __builtin_amdgcn_rcpf(x); }

// tanh via exp2: tanh(y) = 1 - 2/(1 + 2^(y*2log2e)). Caller passes a2 = y*C2L2E
// (bias pre-folded into the fma forming a2). Saturates correctly; err ~1e-7.
__device__ __forceinline__ float tanh_from_arg(float a2){
  float u = __builtin_amdgcn_exp2f(a2);
  return fmaf(-2.0f, rcp_fast(u + 1.0f), 1.0f);
}
__device__ __forceinline__ float tanh_e(float x){ return tanh_from_arg(x * C2L2E); }

__device__ __forceinline__ void make_frag1(const float* vals, v8h& hv){
  #pragma unroll
  for (int j = 0; j < 8; j++) hv[j] = (_Float16)vals[j];
}
__device__ __forceinline__ void make_frag2(const float* vals, v8h& hv, v8h& lv){
  #pragma unroll
  for (int j = 0; j < 8; j++){
    _Float16 h = (_Float16)vals[j];
    hv[j] = h;
    lv[j] = (_Float16)(vals[j] - (float)h);
  }
}

// Role split:
//   waves 0-3 (ABC-waves): layers L0/L1/L2, each wave owns 32 cols (n0 and n0+64).
//       One ds_read of the activation tile serves BOTH col-groups -> LDS read
//       traffic halves vs 8-wave-all-compute (the broadcast-duplication fix).
//   waves 4-7 (D-waves): alpha/beta/h for 16 units each; hreg lives here.
//       wave 5: x-norm (C-interval); wave 6: wout (C-interval).
// Register overlay: D-wave fragments are stored in the SAME arrays (F0/F1) as
// ABC-wave weight frags -- disjoint role paths share one static allocation,
// keeping the kernel under the 256-VGPR / 2-waves-per-SIMD budget.
__global__ __launch_bounds__(512, 2) void lmsc_kernel(
    const float* __restrict__ x, const float* __restrict__ initF,
    const float* __restrict__ w10, const float* __restrict__ b10,
    const float* __restrict__ w20, const float* __restrict__ b20,
    const float* __restrict__ w11, const float* __restrict__ b11,
    const float* __restrict__ w21, const float* __restrict__ b21,
    const float* __restrict__ w12, const float* __restrict__ b12,
    const float* __restrict__ w22, const float* __restrict__ b22,
    const float* __restrict__ wa, const float* __restrict__ ba,
    const float* __restrict__ wb, const float* __restrict__ bb,
    const float* __restrict__ wo,
    float* __restrict__ outs, float* __restrict__ alph)
{
  // ---- LDS: ~20 KB ----
  __shared__ __attribute__((aligned(16))) _Float16 c0[2][SPB*LDK0];  // t-parity double buffer
  __shared__ __attribute__((aligned(16))) _Float16 cP[SPB*LDK];
  __shared__ __attribute__((aligned(16))) _Float16 cQ[SPB*LDK];
  __shared__ __attribute__((aligned(16))) _Float16 cG[SPB*LDK];
  __shared__ __attribute__((aligned(16))) float nrm[2][SPB];         // stores -log2e * ||x||

  const int tid = threadIdx.x;
  const int wv = tid >> 6;       // wave 0..7
  const int ln = tid & 63;
  const int mn = ln & 15;
  const int qd = ln >> 4;
  const int q8 = qd * 8;
  const int sgbase = (int)blockIdx.x * SPB;

  const bool role_abc = (wv < 4);
  const int n0 = wv * 16 + mn;        // ABC-waves: col group 0 (0..63)
  const int n1 = n0 + 64;             //            col group 1 (64..127)
  const int u  = (wv & 3) * 16 + mn;  // D-waves: unit index (0..63)

  float tmp[8];

  // ---------------- overlaid register fragments ----------------
  // role_abc: F0 = B0 frags [g*6+kf*2+br], F1 = B1 [g*8+kf*2+br], F2 = B2.
  // D-waves : F0[0..3]=Bah, F0[4..7]=Bal, F0[8..11]=Bbh; F1[0..1]=wout (wave 6).
  // EB: role_abc: [0..3]=L0 exp2-biases (g0a,g0b,g1a,g1b), [4..7]=L1, [8..11]=L2 raw.
  //     D-waves : [0]=ba[u], [1]=bb[u].
  v8h F0[12], F1[16], F2[16];
  float EB[12];

  if (role_abc){
    #pragma unroll
    for (int g = 0; g < 2; g++){
      const int nc = g ? n1 : n0;
      #pragma unroll
      for (int kf = 0; kf < 3; kf++)
        #pragma unroll
        for (int br = 0; br < 2; br++){
          const float* W = br ? w20 : w10;
          #pragma unroll
          for (int j = 0; j < 8; j++){
            int k = kf*32 + q8 + j;
            int r = (k < 6) ? k : ((k >= 8 && k < 72) ? (k - 2) : -1);
            tmp[j] = (r >= 0) ? W[r*WIDTH + nc] : 0.0f;
          }
          make_frag1(tmp, F0[g*6 + kf*2 + br]);
        }
      #pragma unroll
      for (int kf = 0; kf < 4; kf++)
        #pragma unroll
        for (int br = 0; br < 2; br++){
          const float* W = br ? w21 : w11;
          #pragma unroll
          for (int j = 0; j < 8; j++)
            tmp[j] = W[(kf*32 + q8 + j)*WIDTH + nc];
          make_frag1(tmp, F1[g*8 + kf*2 + br]);
          const float* V = br ? w22 : w12;
          #pragma unroll
          for (int j = 0; j < 8; j++)
            tmp[j] = V[(kf*32 + q8 + j)*WIDTH + nc];
          make_frag1(tmp, F2[g*8 + kf*2 + br]);
        }
      EB[g*2 + 0] = b10[nc] * C2L2E;
      EB[g*2 + 1] = b20[nc] * C2L2E;
      EB[4 + g*2 + 0] = b11[nc] * C2L2E;
      EB[4 + g*2 + 1] = b21[nc] * C2L2E;
      EB[8 + g*2 + 0] = b12[nc];
      EB[8 + g*2 + 1] = b22[nc];
    }
  } else {
    #pragma unroll
    for (int kf = 0; kf < 4; kf++){
      #pragma unroll
      for (int j = 0; j < 8; j++)
        tmp[j] = wa[(kf*32 + q8 + j)*UNITS + u];
      make_frag2(tmp, F0[kf], F0[4 + kf]);
      #pragma unroll
      for (int j = 0; j < 8; j++)
        tmp[j] = wb[(kf*32 + q8 + j)*UNITS + u];
      make_frag1(tmp, F0[8 + kf]);
    }
    EB[0] = ba[u];
    EB[1] = bb[u];
    if (wv == 6){
      #pragma unroll
      for (int j = 0; j < 8; j++)
        tmp[j] = (mn < DOUT) ? wo[(q8 + j)*DOUT + mn] : 0.0f;
      make_frag1(tmp, F1[0]);
      #pragma unroll
      for (int j = 0; j < 8; j++)
        tmp[j] = (mn < DOUT) ? wo[(32 + q8 + j)*DOUT + mn] : 0.0f;
      make_frag1(tmp, F1[1]);
    }
  }

  // hoisted global-store bases (loop-invariant 64-bit address math)
  float* alp  = alph + ((size_t)(sgbase + qd*4) * TB) * UNITS + u;          // D-waves
  float* outp = outs + ((size_t)(sgbase + qd*4) * TB) * DOUT + mn;          // wave 6

  // ---------------- init ----------------
  for (int i = tid; i < 2*SPB*LDK0; i += 512) c0[0][i] = (_Float16)0.0f;
  __syncthreads();

  // h persistent in registers of D-waves (col=unit=u, row=sample=qd*4+r)
  float hreg[4];
  if (!role_abc){
    #pragma unroll
    for (int r = 0; r < 4; r++){
      int s = qd*4 + r;
      float v = initF[(size_t)(sgbase + s)*(2 + UNITS) + 2 + u];
      hreg[r] = v;
      c0[0][s*LDK0 + 8 + u] = (_Float16)v;
    }
  }
  float xv0=0, xv1=0, xv2=0, xv3=0, xv4=0, xv5=0;
  if (wv == 5 && ln < 16){
    const float* xp = x + (size_t)(sgbase + ln)*TB*D_IN;
    float a0=xp[0], a1=xp[1], a2=xp[2], a3=xp[3], a4=xp[4], a5=xp[5];
    float nv = sqrtf(a0*a0 + a1*a1 + a2*a2 + a3*a3 + a4*a4 + a5*a5);
    nrm[0][ln] = nv * NEGL2E;
    float inv = 1.0f / (nv + EPSF);
    c0[0][ln*LDK0 + 0] = (_Float16)(a0*inv);
    c0[0][ln*LDK0 + 1] = (_Float16)(a1*inv);
    c0[0][ln*LDK0 + 2] = (_Float16)(a2*inv);
    c0[0][ln*LDK0 + 3] = (_Float16)(a3*inv);
    c0[0][ln*LDK0 + 4] = (_Float16)(a4*inv);
    c0[0][ln*LDK0 + 5] = (_Float16)(a5*inv);
    xv0 = xp[6]; xv1 = xp[7]; xv2 = xp[8]; xv3 = xp[9]; xv4 = xp[10]; xv5 = xp[11];  // x(t=1)
  }
  __syncthreads();

  auto wout_phase = [&](const _Float16* cb, int tt){
    v8h ah0 = *(const v8h*)(cb + mn*LDK0 + 8 + q8);
    v8h ah1 = *(const v8h*)(cb + mn*LDK0 + 40 + q8);
    v4f acc = {0.f, 0.f, 0.f, 0.f};
    acc = MFMAH(ah0, F1[0], acc);
    acc = MFMAH(ah1, F1[1], acc);
    if (mn < DOUT){
      #pragma unroll
      for (int r = 0; r < 4; r++)
        outp[(size_t)r*TB*DOUT + (size_t)tt*DOUT] = acc[r];
    }
  };

  // ================= time loop (4 LDS-only barriers/step) =================
  for (int t = 0; t < TB; t++){
    const int p = t & 1;
    const _Float16* c0r = c0[p];
    _Float16* c0w = c0[p ^ 1];

    // ---- Phase A: L0 (c0[p] -> cP), ABC-waves, 2 col-groups sharing ah ----
    if (role_abc){
      v8h ah[3];
      #pragma unroll
      for (int kf = 0; kf < 3; kf++)
        ah[kf] = *(const v8h*)(c0r + mn*LDK0 + kf*32 + q8);
      v4f ac[2][2];
      #pragma unroll
      for (int g = 0; g < 2; g++)
        #pragma unroll
        for (int br = 0; br < 2; br++)
          ac[g][br] = (v4f){0.f, 0.f, 0.f, 0.f};
      #pragma unroll
      for (int kf = 0; kf < 3; kf++)
        #pragma unroll
        for (int g = 0; g < 2; g++){
          ac[g][0] = MFMAH(ah[kf], F0[g*6 + kf*2 + 0], ac[g][0]);
          ac[g][1] = MFMAH(ah[kf], F0[g*6 + kf*2 + 1], ac[g][1]);
        }
      #pragma unroll
      for (int r = 0; r < 4; r++){
        const int row = (qd*4 + r)*LDK;
        #pragma unroll
        for (int g = 0; g < 2; g++){
          float t0 = tanh_from_arg(fmaf(ac[g][0][r], C2L2E, EB[g*2 + 0]));
          float t1 = tanh_from_arg(fmaf(ac[g][1][r], C2L2E, EB[g*2 + 1]));
          cP[row + (g ? n1 : n0)] = (_Float16)(t0 * t1);
        }
      }
    }
    BARRIER_LDS();  // b1

    // ---- Phase B: L1 (cP -> cQ), ABC-waves ----
    if (role_abc){
      v8h ah[4];
      #pragma unroll
      for (int kf = 0; kf < 4; kf++)
        ah[kf] = *(const v8h*)(cP + mn*LDK + kf*32 + q8);
      v4f ac[2][2];
      #pragma unroll
      for (int g = 0; g < 2; g++)
        #pragma unroll
        for (int br = 0; br < 2; br++)
          ac[g][br] = (v4f){0.f, 0.f, 0.f, 0.f};
      #pragma unroll
      for (int kf = 0; kf < 4; kf++)
        #pragma unroll
        for (int g = 0; g < 2; g++){
          ac[g][0] = MFMAH(ah[kf], F1[g*8 + kf*2 + 0], ac[g][0]);
          ac[g][1] = MFMAH(ah[kf], F1[g*8 + kf*2 + 1], ac[g][1]);
        }
      #pragma unroll
      for (int r = 0; r < 4; r++){
        const int row = (qd*4 + r)*LDK;
        #pragma unroll
        for (int g = 0; g < 2; g++){
          float t0 = tanh_from_arg(fmaf(ac[g][0][r], C2L2E, EB[4 + g*2 + 0]));
          float t1 = tanh_from_arg(fmaf(ac[g][1][r], C2L2E, EB[4 + g*2 + 1]));
          cQ[row + (g ? n1 : n0)] = (_Float16)(t0 * t1);
        }
      }
    }
    BARRIER_LDS();  // b2

    // ---- Phase C interval:
    //   ABC-waves: L2 (cQ -> cG), g = tanh(x1*x2)
    //   wave 5:    x-norm(t+1) -> c0w, prefetch x(t+2)   (c0w xn-cols: no reader
    //              until A(t+1), ordered by b3+b4)
    //   wave 6:    wout(t-1) from c0r (stable all step)
    if (role_abc){
      v8h ah[4];
      #pragma unroll
      for (int kf = 0; kf < 4; kf++)
        ah[kf] = *(const v8h*)(cQ + mn*LDK + kf*32 + q8);
      v4f ac[2][2];
      #pragma unroll
      for (int g = 0; g < 2; g++)
        #pragma unroll
        for (int br = 0; br < 2; br++){
          float b = EB[8 + g*2 + br];
          ac[g][br] = (v4f){b, b, b, b};
        }
      #pragma unroll
      for (int kf = 0; kf < 4; kf++)
        #pragma unroll
        for (int g = 0; g < 2; g++){
          ac[g][0] = MFMAH(ah[kf], F2[g*8 + kf*2 + 0], ac[g][0]);
          ac[g][1] = MFMAH(ah[kf], F2[g*8 + kf*2 + 1], ac[g][1]);
        }
      #pragma unroll
      for (int r = 0; r < 4; r++){
        const int row = (qd*4 + r)*LDK;
        #pragma unroll
        for (int g = 0; g < 2; g++)
          cG[row + (g ? n1 : n0)] = (_Float16)tanh_e(ac[g][0][r] * ac[g][1][r]);
      }
    } else if (wv == 5 && ln < 16){
      float nv2 = sqrtf(xv0*xv0 + xv1*xv1 + xv2*xv2 + xv3*xv3 + xv4*xv4 + xv5*xv5);
      nrm[p ^ 1][ln] = nv2 * NEGL2E;
      float inv = 1.0f / (nv2 + EPSF);
      c0w[ln*LDK0 + 0] = (_Float16)(xv0*inv);
      c0w[ln*LDK0 + 1] = (_Float16)(xv1*inv);
      c0w[ln*LDK0 + 2] = (_Float16)(xv2*inv);
      c0w[ln*LDK0 + 3] = (_Float16)(xv3*inv);
      c0w[ln*LDK0 + 4] = (_Float16)(xv4*inv);
      c0w[ln*LDK0 + 5] = (_Float16)(xv5*inv);
      int tn = t + 2; if (tn > TB - 1) tn = TB - 1;
      const float* xp = x + ((size_t)(sgbase + ln)*TB + (size_t)tn)*D_IN;
      xv0 = xp[0]; xv1 = xp[1]; xv2 = xp[2]; xv3 = xp[3]; xv4 = xp[4]; xv5 = xp[5];
    } else if (wv == 6){
      if (t > 0) wout_phase(c0r, t - 1);
    }
    BARRIER_LDS();  // b3

    // ---- Phase D: D-waves: pA (wa hi+lo) + pB for 16 units each;
    //      h-update in regs; h(t) -> c0[p^1]; alpha -> global (un-drained store)
    if (!role_abc){
      v8h gh[4];
      #pragma unroll
      for (int kf = 0; kf < 4; kf++)
        gh[kf] = *(const v8h*)(cG + mn*LDK + kf*32 + q8);
      v4f pA0 = {EB[0], EB[0], EB[0], EB[0]};
      v4f pA1 = {0.f, 0.f, 0.f, 0.f};
      v4f pB  = {EB[1], EB[1], EB[1], EB[1]};
      #pragma unroll
      for (int kf = 0; kf < 2; kf++){
        pA0 = MFMAH(gh[kf],   F0[kf],       pA0);   // Bah[kf]
        pA0 = MFMAH(gh[kf],   F0[4 + kf],   pA0);   // Bal[kf]
        pA1 = MFMAH(gh[kf+2], F0[kf + 2],   pA1);   // Bah[kf+2]
        pA1 = MFMAH(gh[kf+2], F0[6 + kf],   pA1);   // Bal[kf+2]
        pB  = MFMAH(gh[2*kf],   F0[8 + 2*kf],   pB);
        pB  = MFMAH(gh[2*kf+1], F0[8 + 2*kf+1], pB);
      }
      #pragma unroll
      for (int r = 0; r < 4; r++){
        int s = qd*4 + r;
        float m = nrm[p][s];                                   // -log2e * norm
        float alpha = __builtin_amdgcn_exp2f((pA0[r] + pA1[r]) * L2E);
        float beta  = tanh_e(pB[r]);
        float dec   = __builtin_amdgcn_exp2f(alpha * m);       // exp(-alpha*norm)
        float h = fmaf(dec, hreg[r] - beta, beta);
        hreg[r] = h;
        c0w[s*LDK0 + 8 + u] = (_Float16)h;
        alp[(size_t)r*TB*UNITS] = alpha;
      }
      alp += UNITS;
    }
    BARRIER_LDS();  // b4
  }

  // final wout(TB-1): h(TB-1) sits in c0[0] (TB even)
  if (wv == 6) wout_phase(c0[0], TB - 1);
}

extern "C" void kernel_launch(void* const* d_in, const int* in_sizes, int n_in,
                              void* d_out, int out_size, void* d_ws, size_t ws_size,
                              hipStream_t stream) {
  const float* x    = (const float*)d_in[0];
  const float* iF   = (const float*)d_in[1];
  const float* w10  = (const float*)d_in[2];
  const float* b10  = (const float*)d_in[3];
  const float* w20  = (const float*)d_in[4];
  const float* b20  = (const float*)d_in[5];
  const float* w11  = (const float*)d_in[6];
  const float* b11  = (const float*)d_in[7];
  const float* w21  = (const float*)d_in[8];
  const float* b21  = (const float*)d_in[9];
  const float* w12  = (const float*)d_in[10];
  const float* b12  = (const float*)d_in[11];
  const float* w22  = (const float*)d_in[12];
  const float* b22  = (const float*)d_in[13];
  const float* wa   = (const float*)d_in[14];
  const float* ba   = (const float*)d_in[15];
  const float* wb   = (const float*)d_in[16];
  const float* bb   = (const float*)d_in[17];
  const float* wo   = (const float*)d_in[18];

  float* outs = (float*)d_out;
  float* alph = outs + (size_t)NB*TB*DOUT;

  lmsc_kernel<<<NB/SPB, 512, 0, stream>>>(x, iF,
      w10, b10, w20, b20, w11, b11, w21, b21, w12, b12, w22, b22,
      wa, ba, wb, bb, wo, outs, alph);
}

// Round 7
// 2291.325 us; speedup vs baseline: 1.1828x; 1.1828x over previous
//
#include <hip/hip_runtime.h>
#include <stdint.h>
#include <stddef.h>

#define NB 1024
#define TB 1024
#define D_IN 6
#define UNITS 64
#define WIDTH 128
#define DOUT 6
#define EPSF 1e-8f
#define SPB 16          // samples per block (one 16-row MFMA tile) -- 64 blocks
#define LDK0 108        // c0 row stride (halfs): conflict-free (54 dw == 22 mod 32)
#define LDK 140         // cP/cQ/cG row stride (halfs): conflict-free (70 dw == 6 mod 32)

typedef _Float16 v8h __attribute__((ext_vector_type(8)));
typedef float v4f __attribute__((ext_vector_type(4)));

#define MFMAH(A,Bf,C) __builtin_amdgcn_mfma_f32_16x16x32_f16((A),(Bf),(C),0,0,0)

// LDS-only barrier: orders LDS across the block, does NOT drain vmcnt.
#define BARRIER_LDS() asm volatile("s_waitcnt lgkmcnt(0)\n\ts_barrier" ::: "memory")

#define C2L2E  2.8853900817779268f    // 2*log2(e)
#define L2E    1.4426950408889634f    // log2(e)
#define NEGL2E (-1.4426950408889634f)

__device__ __forceinline__ float rcp_fast(float x){ return __builtin_amdgcn_rcpf(x); }

// tanh with the 2log2e factor PRE-FOLDED into weights+bias:
// tanh(y) = 1 - 2/(1 + 2^(y*2log2e)); caller passes a2 = y*2log2e (from MFMA).
__device__ __forceinline__ float tanh_from_arg(float a2){
  float u = __builtin_amdgcn_exp2f(a2);
  return fmaf(-2.0f, rcp_fast(u + 1.0f), 1.0f);
}

__device__ __forceinline__ void make_frag1(const float* vals, v8h& hv){
  #pragma unroll
  for (int j = 0; j < 8; j++) hv[j] = (_Float16)vals[j];
}
__device__ __forceinline__ void make_frag2(const float* vals, v8h& hv, v8h& lv){
  #pragma unroll
  for (int j = 0; j < 8; j++){
    _Float16 h = (_Float16)vals[j];
    hv[j] = h;
    lv[j] = (_Float16)(vals[j] - (float)h);
  }
}

__global__ __launch_bounds__(512, 2) void lmsc_kernel(
    const float* __restrict__ x, const float* __restrict__ initF,
    const float* __restrict__ w10, const float* __restrict__ b10,
    const float* __restrict__ w20, const float* __restrict__ b20,
    const float* __restrict__ w11, const float* __restrict__ b11,
    const float* __restrict__ w21, const float* __restrict__ b21,
    const float* __restrict__ w12, const float* __restrict__ b12,
    const float* __restrict__ w22, const float* __restrict__ b22,
    const float* __restrict__ wa, const float* __restrict__ ba,
    const float* __restrict__ wb, const float* __restrict__ bb,
    const float* __restrict__ wo,
    float* __restrict__ outs, float* __restrict__ alph)
{
  // ---- LDS: ~20 KB ----
  __shared__ __attribute__((aligned(16))) _Float16 c0[2][SPB*LDK0];  // t-parity double buffer
  __shared__ __attribute__((aligned(16))) _Float16 cP[SPB*LDK];
  __shared__ __attribute__((aligned(16))) _Float16 cQ[SPB*LDK];
  __shared__ __attribute__((aligned(16))) _Float16 cG[SPB*LDK];
  __shared__ __attribute__((aligned(16))) float nrm[2][SPB];         // stores -log2e * ||x||

  const int tid = threadIdx.x;
  const int wv = tid >> 6;       // wave 0..7
  const int ln = tid & 63;
  const int mn = ln & 15;
  const int qd = ln >> 4;
  const int q8 = qd * 8;
  const int n  = wv * 16 + mn;   // col for WIDTH=128 layers (wave owns 16 cols)
  const int sgbase = (int)blockIdx.x * SPB;

  float tmp[8];

  // ---------------- one-time weight fragments (registers) ----------------
  // All exp2-feeding weights are PRE-SCALED so the MFMA emits the exp2 arg
  // directly (kills per-element fma/mul in every phase tail):
  //   L0/L1 both branches, L2 branch0: * 2log2e;  wa: * log2e;  wb: * 2log2e.
  // f16 rounding is scale-invariant -> no accuracy change.

  // L0: K through c0 cols (xn 0..5, h 8..71), 3 kf
  v8h B0[3][2];
  #pragma unroll
  for (int kf = 0; kf < 3; kf++)
    #pragma unroll
    for (int br = 0; br < 2; br++){
      const float* W = br ? w20 : w10;
      #pragma unroll
      for (int j = 0; j < 8; j++){
        int k = kf*32 + q8 + j;
        int r = (k < 6) ? k : ((k >= 8 && k < 72) ? (k - 2) : -1);
        tmp[j] = (r >= 0) ? W[r*WIDTH + n] * C2L2E : 0.0f;
      }
      make_frag1(tmp, B0[kf][br]);
    }

  // L1 (both branches *2log2e), L2 (branch0 *2log2e, branch1 raw)
  v8h B1[4][2], B2[4][2];
  #pragma unroll
  for (int kf = 0; kf < 4; kf++)
    #pragma unroll
    for (int br = 0; br < 2; br++){
      const float* W = br ? w21 : w11;
      #pragma unroll
      for (int j = 0; j < 8; j++)
        tmp[j] = W[(kf*32 + q8 + j)*WIDTH + n] * C2L2E;
      make_frag1(tmp, B1[kf][br]);
      const float* V = br ? w22 : w12;
      const float sc = br ? 1.0f : C2L2E;
      #pragma unroll
      for (int j = 0; j < 8; j++)
        tmp[j] = V[(kf*32 + q8 + j)*WIDTH + n] * sc;
      make_frag1(tmp, B2[kf][br]);
    }

  // D-phase: wave (wv&3) owns units u..u+15; wa hi+lo (*log2e), wb single (*2log2e)
  const int u = (wv & 3) * 16 + mn;
  v8h Bah[4], Bal[4], Bbh[4];
  #pragma unroll
  for (int kf = 0; kf < 4; kf++){
    #pragma unroll
    for (int j = 0; j < 8; j++)
      tmp[j] = wa[(kf*32 + q8 + j)*UNITS + u] * L2E;
    make_frag2(tmp, Bah[kf], Bal[kf]);
    #pragma unroll
    for (int j = 0; j < 8; j++)
      tmp[j] = wb[(kf*32 + q8 + j)*UNITS + u] * C2L2E;
    make_frag1(tmp, Bbh[kf]);
  }
  const float bsa = ba[u] * L2E;     // alpha = exp2(pA)
  const float bsb = bb[u] * C2L2E;   // beta  = tanh_from_arg(pB)

  // wout (K=64 over h, N=6 padded to 16): single fp16 (used by wave 7)
  v8h Woh0, Woh1;
  #pragma unroll
  for (int j = 0; j < 8; j++)
    tmp[j] = (mn < DOUT) ? wo[(q8 + j)*DOUT + mn] : 0.0f;
  make_frag1(tmp, Woh0);
  #pragma unroll
  for (int j = 0; j < 8; j++)
    tmp[j] = (mn < DOUT) ? wo[(32 + q8 + j)*DOUT + mn] : 0.0f;
  make_frag1(tmp, Woh1);

  // biases as acc-init splats (already in exp2-arg scale)
  const float e0a = b10[n] * C2L2E, e0b = b20[n] * C2L2E;
  const float e1a = b11[n] * C2L2E, e1b = b21[n] * C2L2E;
  const float e2a = b12[n] * C2L2E, e2b = b22[n];

  // hoisted global-store bases (loop-invariant 64-bit address math)
  float* alp  = alph + ((size_t)(sgbase + qd*4) * TB) * UNITS + u;          // waves 0-3
  float* outp = outs + ((size_t)(sgbase + qd*4) * TB) * DOUT + mn;          // wave 7

  // ---------------- init ----------------
  for (int i = tid; i < 2*SPB*LDK0; i += 512) c0[0][i] = (_Float16)0.0f;
  __syncthreads();

  // h persistent in registers of waves 0-3 (C-layout: col=unit=u, row=sample=qd*4+r)
  float hreg[4];
  if (wv < 4){
    #pragma unroll
    for (int r = 0; r < 4; r++){
      int s = qd*4 + r;
      float v = initF[(size_t)(sgbase + s)*(2 + UNITS) + 2 + u];
      hreg[r] = v;
      c0[0][s*LDK0 + 8 + u] = (_Float16)v;
    }
  }
  float xv0=0, xv1=0, xv2=0, xv3=0, xv4=0, xv5=0;
  if (wv == 4 && ln < 16){
    const float* xp = x + (size_t)(sgbase + ln)*TB*D_IN;
    float a0=xp[0], a1=xp[1], a2=xp[2], a3=xp[3], a4=xp[4], a5=xp[5];
    float nv = sqrtf(a0*a0 + a1*a1 + a2*a2 + a3*a3 + a4*a4 + a5*a5);
    nrm[0][ln] = nv * NEGL2E;
    float inv = 1.0f / (nv + EPSF);
    c0[0][ln*LDK0 + 0] = (_Float16)(a0*inv);
    c0[0][ln*LDK0 + 1] = (_Float16)(a1*inv);
    c0[0][ln*LDK0 + 2] = (_Float16)(a2*inv);
    c0[0][ln*LDK0 + 3] = (_Float16)(a3*inv);
    c0[0][ln*LDK0 + 4] = (_Float16)(a4*inv);
    c0[0][ln*LDK0 + 5] = (_Float16)(a5*inv);
    xv0 = xp[6]; xv1 = xp[7]; xv2 = xp[8]; xv3 = xp[9]; xv4 = xp[10]; xv5 = xp[11];  // x(t=1)
  }
  __syncthreads();

  auto wout_phase = [&](const _Float16* cb, int tt){
    v8h ah0 = *(const v8h*)(cb + mn*LDK0 + 8 + q8);
    v8h ah1 = *(const v8h*)(cb + mn*LDK0 + 40 + q8);
    v4f acc = {0.f, 0.f, 0.f, 0.f};
    acc = MFMAH(ah0, Woh0, acc);
    acc = MFMAH(ah1, Woh1, acc);
    if (mn < DOUT){
      #pragma unroll
      for (int r = 0; r < 4; r++)
        outp[(size_t)r*TB*DOUT + (size_t)tt*DOUT] = acc[r];
    }
  };

  // ================= time loop (4 LDS-only barriers/step) =================
  for (int t = 0; t < TB; t++){
    const int p = t & 1;
    const _Float16* c0r = c0[p];
    _Float16* c0w = c0[p ^ 1];

    // ---- Phase A: L0 (c0[p] -> cP) ----
    // tanh(y1)*tanh(y2) = (p-s+1)/(p+s+1), u_i = 2^(arg_i) straight from MFMA:
    // 2 exp2 + 1 rcp per pair (vs 2 exp2 + 2 rcp + 2 fma before).
    {
      v8h ah[3];
      #pragma unroll
      for (int kf = 0; kf < 3; kf++)
        ah[kf] = *(const v8h*)(c0r + mn*LDK0 + kf*32 + q8);
      v4f acc0 = {e0a, e0a, e0a, e0a};
      v4f acc1 = {e0b, e0b, e0b, e0b};
      #pragma unroll
      for (int kf = 0; kf < 3; kf++){
        acc0 = MFMAH(ah[kf], B0[kf][0], acc0);
        acc1 = MFMAH(ah[kf], B0[kf][1], acc1);
      }
      #pragma unroll
      for (int r = 0; r < 4; r++){
        float u0 = __builtin_amdgcn_exp2f(acc0[r]);
        float u1 = __builtin_amdgcn_exp2f(acc1[r]);
        float pr = u0 * u1;
        float sm = u0 + u1;
        float pp = pr + 1.0f;
        float res = (pp - sm) * rcp_fast(pp + sm);
        cP[(qd*4 + r)*LDK + n] = (_Float16)res;
      }
    }
    BARRIER_LDS();  // b1

    // ---- Phase B: L1 (cP -> cQ), same product-form pair ----
    {
      v8h ah[4];
      #pragma unroll
      for (int kf = 0; kf < 4; kf++)
        ah[kf] = *(const v8h*)(cP + mn*LDK + kf*32 + q8);
      v4f acc0 = {e1a, e1a, e1a, e1a};
      v4f acc1 = {e1b, e1b, e1b, e1b};
      #pragma unroll
      for (int kf = 0; kf < 4; kf++){
        acc0 = MFMAH(ah[kf], B1[kf][0], acc0);
        acc1 = MFMAH(ah[kf], B1[kf][1], acc1);
      }
      #pragma unroll
      for (int r = 0; r < 4; r++){
        float u0 = __builtin_amdgcn_exp2f(acc0[r]);
        float u1 = __builtin_amdgcn_exp2f(acc1[r]);
        float pr = u0 * u1;
        float sm = u0 + u1;
        float pp = pr + 1.0f;
        float res = (pp - sm) * rcp_fast(pp + sm);
        cQ[(qd*4 + r)*LDK + n] = (_Float16)res;
      }
    }
    BARRIER_LDS();  // b2

    // ---- Phase C: L2 (cQ -> g), g = tanh(x1*x2); 2log2e folded into branch0 ----
    {
      v8h ah[4];
      #pragma unroll
      for (int kf = 0; kf < 4; kf++)
        ah[kf] = *(const v8h*)(cQ + mn*LDK + kf*32 + q8);
      v4f acc0 = {e2a, e2a, e2a, e2a};
      v4f acc1 = {e2b, e2b, e2b, e2b};
      #pragma unroll
      for (int kf = 0; kf < 4; kf++){
        acc0 = MFMAH(ah[kf], B2[kf][0], acc0);
        acc1 = MFMAH(ah[kf], B2[kf][1], acc1);
      }
      #pragma unroll
      for (int r = 0; r < 4; r++)
        cG[(qd*4 + r)*LDK + n] = (_Float16)tanh_from_arg(acc0[r] * acc1[r]);
    }
    BARRIER_LDS();  // b3

    // ---- Phase D:
    //   waves 0-3: pA (wa hi+lo) + pB for 16 units; h-update in regs;
    //              h(t) -> c0[p^1], alpha -> global (un-drained store)
    //   wave 7:    wout(t-1) from c0[p]
    //   wave 4:    x-norm(t+1) -> c0[p^1], prefetch x(t+2)
    if (wv < 4){
      v8h gh[4];
      #pragma unroll
      for (int kf = 0; kf < 4; kf++)
        gh[kf] = *(const v8h*)(cG + mn*LDK + kf*32 + q8);
      v4f pA0 = {bsa, bsa, bsa, bsa};
      v4f pA1 = {0.f, 0.f, 0.f, 0.f};
      v4f pB  = {bsb, bsb, bsb, bsb};
      #pragma unroll
      for (int kf = 0; kf < 2; kf++){
        pA0 = MFMAH(gh[kf], Bah[kf], pA0);
        pA0 = MFMAH(gh[kf], Bal[kf], pA0);
        pA1 = MFMAH(gh[kf+2], Bah[kf+2], pA1);
        pA1 = MFMAH(gh[kf+2], Bal[kf+2], pA1);
        pB  = MFMAH(gh[2*kf],   Bbh[2*kf],   pB);
        pB  = MFMAH(gh[2*kf+1], Bbh[2*kf+1], pB);
      }
      #pragma unroll
      for (int r = 0; r < 4; r++){
        int s = qd*4 + r;
        float m = nrm[p][s];                                   // -log2e * norm
        float alpha = __builtin_amdgcn_exp2f(pA0[r] + pA1[r]); // wa,ba pre-scaled
        float beta  = tanh_from_arg(pB[r]);                    // wb,bb pre-scaled
        float dec   = __builtin_amdgcn_exp2f(alpha * m);       // exp(-alpha*norm)
        float h = fmaf(dec, hreg[r] - beta, beta);
        hreg[r] = h;
        c0w[s*LDK0 + 8 + u] = (_Float16)h;
        alp[(size_t)r*TB*UNITS] = alpha;
      }
      alp += UNITS;
    } else if (wv == 7){
      if (t > 0) wout_phase(c0r, t - 1);
    } else if (wv == 4 && ln < 16){
      float nv2 = sqrtf(xv0*xv0 + xv1*xv1 + xv2*xv2 + xv3*xv3 + xv4*xv4 + xv5*xv5);
      nrm[p ^ 1][ln] = nv2 * NEGL2E;
      float inv = 1.0f / (nv2 + EPSF);
      c0w[ln*LDK0 + 0] = (_Float16)(xv0*inv);
      c0w[ln*LDK0 + 1] = (_Float16)(xv1*inv);
      c0w[ln*LDK0 + 2] = (_Float16)(xv2*inv);
      c0w[ln*LDK0 + 3] = (_Float16)(xv3*inv);
      c0w[ln*LDK0 + 4] = (_Float16)(xv4*inv);
      c0w[ln*LDK0 + 5] = (_Float16)(xv5*inv);
      int tn = t + 2; if (tn > TB - 1) tn = TB - 1;
      const float* xp = x + ((size_t)(sgbase + ln)*TB + (size_t)tn)*D_IN;
      xv0 = xp[0]; xv1 = xp[1]; xv2 = xp[2]; xv3 = xp[3]; xv4 = xp[4]; xv5 = xp[5];
    }
    BARRIER_LDS();  // b4
  }

  // final wout(TB-1): h(TB-1) sits in c0[0]
  if (wv == 7) wout_phase(c0[TB & 1], TB - 1);
}

extern "C" void kernel_launch(void* const* d_in, const int* in_sizes, int n_in,
                              void* d_out, int out_size, void* d_ws, size_t ws_size,
                              hipStream_t stream) {
  const float* x    = (const float*)d_in[0];
  const float* iF   = (const float*)d_in[1];
  const float* w10  = (const float*)d_in[2];
  const float* b10  = (const float*)d_in[3];
  const float* w20  = (const float*)d_in[4];
  const float* b20  = (const float*)d_in[5];
  const float* w11  = (const float*)d_in[6];
  const float* b11  = (const float*)d_in[7];
  const float* w21  = (const float*)d_in[8];
  const float* b21  = (const float*)d_in[9];
  const float* w12  = (const float*)d_in[10];
  const float* b12  = (const float*)d_in[11];
  const float* w22  = (const float*)d_in[12];
  const float* b22  = (const float*)d_in[13];
  const float* wa   = (const float*)d_in[14];
  const float* ba   = (const float*)d_in[15];
  const float* wb   = (const float*)d_in[16];
  const float* bb   = (const float*)d_in[17];
  const float* wo   = (const float*)d_in[18];

  float* outs = (float*)d_out;
  float* alph = outs + (size_t)NB*TB*DOUT;

  lmsc_kernel<<<NB/SPB, 512, 0, stream>>>(x, iF,
      w10, b10, w20, b20, w11, b11, w21, b21, w12, b12, w22, b22,
      wa, ba, wb, bb, wo, outs, alph);
}

// Round 8
// 2287.833 us; speedup vs baseline: 1.1846x; 1.0015x over previous
//
#include <hip/hip_runtime.h>
#include <stdint.h>
#include <stddef.h>

#define NB 1024
#define TB 1024
#define D_IN 6
#define UNITS 64
#define WIDTH 128
#define DOUT 6
#define EPSF 1e-8f
#define SPB 16          // samples per block (one 16-row MFMA tile) -- 64 blocks
#define LDK0 108        // c0 row stride (halfs): conflict-free (54 dw == 22 mod 32)
#define LDK 140         // cP/cQ/cG row stride (halfs): conflict-free (70 dw == 6 mod 32)

typedef _Float16 v8h __attribute__((ext_vector_type(8)));
typedef float v4f __attribute__((ext_vector_type(4)));
typedef float v2f __attribute__((ext_vector_type(2)));

#define MFMAH(A,Bf,C) __builtin_amdgcn_mfma_f32_16x16x32_f16((A),(Bf),(C),0,0,0)

// LDS-only barrier: orders LDS across the block, does NOT drain vmcnt.
#define BARRIER_LDS() asm volatile("s_waitcnt lgkmcnt(0)\n\ts_barrier" ::: "memory")

#define C2L2E  2.8853900817779268f    // 2*log2(e)
#define L2E    1.4426950408889634f    // log2(e)
#define NEGL2E (-1.4426950408889634f)

__device__ __forceinline__ float rcp_fast(float x){ return __builtin_amdgcn_rcpf(x); }

// tanh with the 2log2e factor PRE-FOLDED into weights+bias:
// tanh(y) = 1 - 2/(1 + 2^(y*2log2e)); caller passes a2 = y*2log2e (from MFMA).
__device__ __forceinline__ float tanh_from_arg(float a2){
  float u = __builtin_amdgcn_exp2f(a2);
  return fmaf(-2.0f, rcp_fast(u + 1.0f), 1.0f);
}

__device__ __forceinline__ void make_frag1(const float* vals, v8h& hv){
  #pragma unroll
  for (int j = 0; j < 8; j++) hv[j] = (_Float16)vals[j];
}
__device__ __forceinline__ void make_frag2(const float* vals, v8h& hv, v8h& lv){
  #pragma unroll
  for (int j = 0; j < 8; j++){
    _Float16 h = (_Float16)vals[j];
    hv[j] = h;
    lv[j] = (_Float16)(vals[j] - (float)h);
  }
}

__global__ __launch_bounds__(512, 2) void lmsc_kernel(
    const float* __restrict__ x, const float* __restrict__ initF,
    const float* __restrict__ w10, const float* __restrict__ b10,
    const float* __restrict__ w20, const float* __restrict__ b20,
    const float* __restrict__ w11, const float* __restrict__ b11,
    const float* __restrict__ w21, const float* __restrict__ b21,
    const float* __restrict__ w12, const float* __restrict__ b12,
    const float* __restrict__ w22, const float* __restrict__ b22,
    const float* __restrict__ wa, const float* __restrict__ ba,
    const float* __restrict__ wb, const float* __restrict__ bb,
    const float* __restrict__ wo,
    float* __restrict__ outs, float* __restrict__ alph)
{
  // ---- LDS: ~20 KB ----
  __shared__ __attribute__((aligned(16))) _Float16 c0[2][SPB*LDK0];  // t-parity double buffer
  __shared__ __attribute__((aligned(16))) _Float16 cP[SPB*LDK];
  __shared__ __attribute__((aligned(16))) _Float16 cQ[SPB*LDK];
  __shared__ __attribute__((aligned(16))) _Float16 cG[SPB*LDK];
  __shared__ __attribute__((aligned(16))) float nrm[2][SPB];         // stores -log2e * ||x||

  const int tid = threadIdx.x;
  const int wv = tid >> 6;       // wave 0..7
  const int ln = tid & 63;
  const int mn = ln & 15;
  const int qd = ln >> 4;
  const int q8 = qd * 8;
  const int n  = wv * 16 + mn;   // col for WIDTH=128 layers (wave owns 16 cols)
  const int sgbase = (int)blockIdx.x * SPB;

  float tmp[8];

  // ---------------- one-time weight fragments (registers) ----------------
  // All exp2-feeding weights PRE-SCALED so the MFMA emits the exp2 arg directly:
  //   L0/L1 both branches, L2 branch0: * 2log2e;  wa: * log2e;  wb: * 2log2e.
  // f16 rounding is scale-invariant -> no accuracy change.

  // L0: K through c0 cols (xn 0..5, h 8..71), 3 kf
  v8h B0[3][2];
  #pragma unroll
  for (int kf = 0; kf < 3; kf++)
    #pragma unroll
    for (int br = 0; br < 2; br++){
      const float* W = br ? w20 : w10;
      #pragma unroll
      for (int j = 0; j < 8; j++){
        int k = kf*32 + q8 + j;
        int r = (k < 6) ? k : ((k >= 8 && k < 72) ? (k - 2) : -1);
        tmp[j] = (r >= 0) ? W[r*WIDTH + n] * C2L2E : 0.0f;
      }
      make_frag1(tmp, B0[kf][br]);
    }

  // L1 (both branches *2log2e), L2 (branch0 *2log2e, branch1 raw)
  v8h B1[4][2], B2[4][2];
  #pragma unroll
  for (int kf = 0; kf < 4; kf++)
    #pragma unroll
    for (int br = 0; br < 2; br++){
      const float* W = br ? w21 : w11;
      #pragma unroll
      for (int j = 0; j < 8; j++)
        tmp[j] = W[(kf*32 + q8 + j)*WIDTH + n] * C2L2E;
      make_frag1(tmp, B1[kf][br]);
      const float* V = br ? w22 : w12;
      const float sc = br ? 1.0f : C2L2E;
      #pragma unroll
      for (int j = 0; j < 8; j++)
        tmp[j] = V[(kf*32 + q8 + j)*WIDTH + n] * sc;
      make_frag1(tmp, B2[kf][br]);
    }

  // D-phase: wave (wv&3) owns units u..u+15; wa hi+lo (*log2e), wb single (*2log2e)
  const int u = (wv & 3) * 16 + mn;
  v8h Bah[4], Bal[4], Bbh[4];
  #pragma unroll
  for (int kf = 0; kf < 4; kf++){
    #pragma unroll
    for (int j = 0; j < 8; j++)
      tmp[j] = wa[(kf*32 + q8 + j)*UNITS + u] * L2E;
    make_frag2(tmp, Bah[kf], Bal[kf]);
    #pragma unroll
    for (int j = 0; j < 8; j++)
      tmp[j] = wb[(kf*32 + q8 + j)*UNITS + u] * C2L2E;
    make_frag1(tmp, Bbh[kf]);
  }
  const float bsa = ba[u] * L2E;     // alpha = exp2(pA)
  const float bsb = bb[u] * C2L2E;   // beta  = tanh_from_arg(pB)

  // wout (K=64 over h, N=6 padded to 16): single fp16 (used by wave 7)
  v8h Woh0, Woh1;
  #pragma unroll
  for (int j = 0; j < 8; j++)
    tmp[j] = (mn < DOUT) ? wo[(q8 + j)*DOUT + mn] : 0.0f;
  make_frag1(tmp, Woh0);
  #pragma unroll
  for (int j = 0; j < 8; j++)
    tmp[j] = (mn < DOUT) ? wo[(32 + q8 + j)*DOUT + mn] : 0.0f;
  make_frag1(tmp, Woh1);

  // biases as acc-init splats (already in exp2-arg scale)
  const float e0a = b10[n] * C2L2E, e0b = b20[n] * C2L2E;
  const float e1a = b11[n] * C2L2E, e1b = b21[n] * C2L2E;
  const float e2a = b12[n] * C2L2E, e2b = b22[n];

  // hoisted global-store bases (loop-invariant 64-bit address math)
  float* alp  = alph + ((size_t)(sgbase + qd*4) * TB) * UNITS + u;          // waves 0-3
  float* outp = outs + ((size_t)(sgbase + qd*4) * TB) * DOUT + mn;          // wave 7

  // ---------------- init ----------------
  for (int i = tid; i < 2*SPB*LDK0; i += 512) c0[0][i] = (_Float16)0.0f;
  __syncthreads();

  // h persistent in registers of waves 0-3 (C-layout: col=unit=u, row=sample=qd*4+r)
  float hreg[4];
  if (wv < 4){
    #pragma unroll
    for (int r = 0; r < 4; r++){
      int s = qd*4 + r;
      float v = initF[(size_t)(sgbase + s)*(2 + UNITS) + 2 + u];
      hreg[r] = v;
      c0[0][s*LDK0 + 8 + u] = (_Float16)v;
    }
  }
  float xv0=0, xv1=0, xv2=0, xv3=0, xv4=0, xv5=0;
  if (wv == 4 && ln < 16){
    const v2f* xp2 = (const v2f*)(x + (size_t)(sgbase + ln)*TB*D_IN);  // rows 24B -> 8B aligned
    v2f A = xp2[0], Bv = xp2[1], C = xp2[2];
    float nv = sqrtf(A[0]*A[0] + A[1]*A[1] + Bv[0]*Bv[0] + Bv[1]*Bv[1] + C[0]*C[0] + C[1]*C[1]);
    nrm[0][ln] = nv * NEGL2E;
    float inv = 1.0f / (nv + EPSF);
    c0[0][ln*LDK0 + 0] = (_Float16)(A[0]*inv);
    c0[0][ln*LDK0 + 1] = (_Float16)(A[1]*inv);
    c0[0][ln*LDK0 + 2] = (_Float16)(Bv[0]*inv);
    c0[0][ln*LDK0 + 3] = (_Float16)(Bv[1]*inv);
    c0[0][ln*LDK0 + 4] = (_Float16)(C[0]*inv);
    c0[0][ln*LDK0 + 5] = (_Float16)(C[1]*inv);
    v2f D = xp2[3], E = xp2[4], F = xp2[5];                            // x(t=1)
    xv0 = D[0]; xv1 = D[1]; xv2 = E[0]; xv3 = E[1]; xv4 = F[0]; xv5 = F[1];
  }
  __syncthreads();

  auto wout_phase = [&](const _Float16* cb, int tt){
    v8h ah0 = *(const v8h*)(cb + mn*LDK0 + 8 + q8);
    v8h ah1 = *(const v8h*)(cb + mn*LDK0 + 40 + q8);
    v4f acc = {0.f, 0.f, 0.f, 0.f};
    acc = MFMAH(ah0, Woh0, acc);
    acc = MFMAH(ah1, Woh1, acc);
    if (mn < DOUT){
      #pragma unroll
      for (int r = 0; r < 4; r++)
        outp[(size_t)r*TB*DOUT + (size_t)tt*DOUT] = acc[r];
    }
  };

  // ================= time loop (4 LDS-only barriers/step) =================
  for (int t = 0; t < TB; t++){
    const int p = t & 1;
    const _Float16* c0r = c0[p];
    _Float16* c0w = c0[p ^ 1];

    // ---- Phase A: L0 (c0[p] -> cP) ----
    // Split accumulators: 4 independent chains (<=2 deep) instead of 2 chains of 3,
    // so MFMA-latency never stalls a revisit. Merge with v4f adds.
    {
      v8h ah[3];
      #pragma unroll
      for (int kf = 0; kf < 3; kf++)
        ah[kf] = *(const v8h*)(c0r + mn*LDK0 + kf*32 + q8);
      v4f a0a = {e0a, e0a, e0a, e0a}, a0b = {0.f, 0.f, 0.f, 0.f};
      v4f a1a = {e0b, e0b, e0b, e0b}, a1b = {0.f, 0.f, 0.f, 0.f};
      a0a = MFMAH(ah[0], B0[0][0], a0a);
      a1a = MFMAH(ah[0], B0[0][1], a1a);
      a0b = MFMAH(ah[1], B0[1][0], a0b);
      a1b = MFMAH(ah[1], B0[1][1], a1b);
      a0a = MFMAH(ah[2], B0[2][0], a0a);
      a1a = MFMAH(ah[2], B0[2][1], a1a);
      v4f acc0 = a0a + a0b;
      v4f acc1 = a1a + a1b;
      // tanh(y1)*tanh(y2) = (p-s+1)/(p+s+1), u_i = 2^arg_i straight from MFMA.
      #pragma unroll
      for (int r = 0; r < 4; r++){
        float u0 = __builtin_amdgcn_exp2f(acc0[r]);
        float u1 = __builtin_amdgcn_exp2f(acc1[r]);
        float pr = u0 * u1;
        float sm = u0 + u1;
        float pp = pr + 1.0f;
        float res = (pp - sm) * rcp_fast(pp + sm);
        cP[(qd*4 + r)*LDK + n] = (_Float16)res;
      }
    }
    BARRIER_LDS();  // b1

    // ---- Phase B: L1 (cP -> cQ), 4 chains of 2 ----
    {
      v8h ah[4];
      #pragma unroll
      for (int kf = 0; kf < 4; kf++)
        ah[kf] = *(const v8h*)(cP + mn*LDK + kf*32 + q8);
      v4f a0a = {e1a, e1a, e1a, e1a}, a0b = {0.f, 0.f, 0.f, 0.f};
      v4f a1a = {e1b, e1b, e1b, e1b}, a1b = {0.f, 0.f, 0.f, 0.f};
      a0a = MFMAH(ah[0], B1[0][0], a0a);
      a1a = MFMAH(ah[0], B1[0][1], a1a);
      a0b = MFMAH(ah[1], B1[1][0], a0b);
      a1b = MFMAH(ah[1], B1[1][1], a1b);
      a0a = MFMAH(ah[2], B1[2][0], a0a);
      a1a = MFMAH(ah[2], B1[2][1], a1a);
      a0b = MFMAH(ah[3], B1[3][0], a0b);
      a1b = MFMAH(ah[3], B1[3][1], a1b);
      v4f acc0 = a0a + a0b;
      v4f acc1 = a1a + a1b;
      #pragma unroll
      for (int r = 0; r < 4; r++){
        float u0 = __builtin_amdgcn_exp2f(acc0[r]);
        float u1 = __builtin_amdgcn_exp2f(acc1[r]);
        float pr = u0 * u1;
        float sm = u0 + u1;
        float pp = pr + 1.0f;
        float res = (pp - sm) * rcp_fast(pp + sm);
        cQ[(qd*4 + r)*LDK + n] = (_Float16)res;
      }
    }
    BARRIER_LDS();  // b2

    // ---- Phase C: L2 (cQ -> g), g = tanh(x1*x2); 4 chains of 2 ----
    {
      v8h ah[4];
      #pragma unroll
      for (int kf = 0; kf < 4; kf++)
        ah[kf] = *(const v8h*)(cQ + mn*LDK + kf*32 + q8);
      v4f a0a = {e2a, e2a, e2a, e2a}, a0b = {0.f, 0.f, 0.f, 0.f};
      v4f a1a = {e2b, e2b, e2b, e2b}, a1b = {0.f, 0.f, 0.f, 0.f};
      a0a = MFMAH(ah[0], B2[0][0], a0a);
      a1a = MFMAH(ah[0], B2[0][1], a1a);
      a0b = MFMAH(ah[1], B2[1][0], a0b);
      a1b = MFMAH(ah[1], B2[1][1], a1b);
      a0a = MFMAH(ah[2], B2[2][0], a0a);
      a1a = MFMAH(ah[2], B2[2][1], a1a);
      a0b = MFMAH(ah[3], B2[3][0], a0b);
      a1b = MFMAH(ah[3], B2[3][1], a1b);
      v4f acc0 = a0a + a0b;
      v4f acc1 = a1a + a1b;
      #pragma unroll
      for (int r = 0; r < 4; r++)
        cG[(qd*4 + r)*LDK + n] = (_Float16)tanh_from_arg(acc0[r] * acc1[r]);
    }
    BARRIER_LDS();  // b3

    // ---- Phase D:
    //   waves 0-3: pA (wa hi+lo, 4 chains of 2) + pB (2 chains of 2);
    //              h-update in regs; h(t) -> c0[p^1], alpha -> global
    //   wave 7:    wout(t-1) from c0[p]
    //   wave 4:    x-norm(t+1) -> c0[p^1], prefetch x(t+2)
    if (wv < 4){
      v8h gh[4];
      #pragma unroll
      for (int kf = 0; kf < 4; kf++)
        gh[kf] = *(const v8h*)(cG + mn*LDK + kf*32 + q8);
      v4f p0 = {bsa, bsa, bsa, bsa};
      v4f p1 = {0.f, 0.f, 0.f, 0.f};
      v4f p2 = {0.f, 0.f, 0.f, 0.f};
      v4f p3 = {0.f, 0.f, 0.f, 0.f};
      v4f pb0 = {bsb, bsb, bsb, bsb};
      v4f pb1 = {0.f, 0.f, 0.f, 0.f};
      p0 = MFMAH(gh[0], Bah[0], p0);   // hi chains
      p2 = MFMAH(gh[2], Bah[2], p2);
      p1 = MFMAH(gh[0], Bal[0], p1);   // lo chains
      p3 = MFMAH(gh[2], Bal[2], p3);
      pb0 = MFMAH(gh[0], Bbh[0], pb0);
      pb1 = MFMAH(gh[2], Bbh[2], pb1);
      p0 = MFMAH(gh[1], Bah[1], p0);
      p2 = MFMAH(gh[3], Bah[3], p2);
      p1 = MFMAH(gh[1], Bal[1], p1);
      p3 = MFMAH(gh[3], Bal[3], p3);
      pb0 = MFMAH(gh[1], Bbh[1], pb0);
      pb1 = MFMAH(gh[3], Bbh[3], pb1);
      v4f pA = (p0 + p1) + (p2 + p3);
      v4f pB = pb0 + pb1;
      #pragma unroll
      for (int r = 0; r < 4; r++){
        int s = qd*4 + r;
        float m = nrm[p][s];                                   // -log2e * norm
        float alpha = __builtin_amdgcn_exp2f(pA[r]);           // wa,ba pre-scaled
        float beta  = tanh_from_arg(pB[r]);                    // wb,bb pre-scaled
        float dec   = __builtin_amdgcn_exp2f(alpha * m);       // exp(-alpha*norm)
        float h = fmaf(dec, hreg[r] - beta, beta);
        hreg[r] = h;
        c0w[s*LDK0 + 8 + u] = (_Float16)h;
        alp[(size_t)r*TB*UNITS] = alpha;
      }
      alp += UNITS;
    } else if (wv == 7){
      if (t > 0) wout_phase(c0r, t - 1);
    } else if (wv == 4 && ln < 16){
      float nv2 = sqrtf(xv0*xv0 + xv1*xv1 + xv2*xv2 + xv3*xv3 + xv4*xv4 + xv5*xv5);
      nrm[p ^ 1][ln] = nv2 * NEGL2E;
      float inv = 1.0f / (nv2 + EPSF);
      c0w[ln*LDK0 + 0] = (_Float16)(xv0*inv);
      c0w[ln*LDK0 + 1] = (_Float16)(xv1*inv);
      c0w[ln*LDK0 + 2] = (_Float16)(xv2*inv);
      c0w[ln*LDK0 + 3] = (_Float16)(xv3*inv);
      c0w[ln*LDK0 + 4] = (_Float16)(xv4*inv);
      c0w[ln*LDK0 + 5] = (_Float16)(xv5*inv);
      int tn = t + 2; if (tn > TB - 1) tn = TB - 1;
      const v2f* xp2 = (const v2f*)(x + ((size_t)(sgbase + ln)*TB + (size_t)tn)*D_IN);
      v2f D = xp2[0], E = xp2[1], F = xp2[2];
      xv0 = D[0]; xv1 = D[1]; xv2 = E[0]; xv3 = E[1]; xv4 = F[0]; xv5 = F[1];
    }
    BARRIER_LDS();  // b4
  }

  // final wout(TB-1): h(TB-1) sits in c0[0]
  if (wv == 7) wout_phase(c0[TB & 1], TB - 1);
}

extern "C" void kernel_launch(void* const* d_in, const int* in_sizes, int n_in,
                              void* d_out, int out_size, void* d_ws, size_t ws_size,
                              hipStream_t stream) {
  const float* x    = (const float*)d_in[0];
  const float* iF   = (const float*)d_in[1];
  const float* w10  = (const float*)d_in[2];
  const float* b10  = (const float*)d_in[3];
  const float* w20  = (const float*)d_in[4];
  const float* b20  = (const float*)d_in[5];
  const float* w11  = (const float*)d_in[6];
  const float* b11  = (const float*)d_in[7];
  const float* w21  = (const float*)d_in[8];
  const float* b21  = (const float*)d_in[9];
  const float* w12  = (const float*)d_in[10];
  const float* b12  = (const float*)d_in[11];
  const float* w22  = (const float*)d_in[12];
  const float* b22  = (const float*)d_in[13];
  const float* wa   = (const float*)d_in[14];
  const float* ba   = (const float*)d_in[15];
  const float* wb   = (const float*)d_in[16];
  const float* bb   = (const float*)d_in[17];
  const float* wo   = (const float*)d_in[18];

  float* outs = (float*)d_out;
  float* alph = outs + (size_t)NB*TB*DOUT;

  lmsc_kernel<<<NB/SPB, 512, 0, stream>>>(x, iF,
      w10, b10, w20, b20, w11, b11, w21, b21, w12, b12, w22, b22,
      wa, ba, wb, bb, wo, outs, alph);
}